// Round 3
// baseline (5020.272 us; speedup 1.0000x reference)
//
#include <hip/hip_runtime.h>

#define MTOT 131072   // b*n
#define NB   65536    // n per batch

// ---------------------------------------------------------------- pmin
__global__ void pmin_init_kernel(float* pmin){
    if (threadIdx.x < 6) pmin[threadIdx.x] = 2.0f;   // p in [0,1)
}

__global__ void pmin_kernel(const float* __restrict__ p, float* __restrict__ pmin){
    int bi = blockIdx.y;
    float m0 = 2.f, m1 = 2.f, m2 = 2.f;
    for (int ni = blockIdx.x * blockDim.x + threadIdx.x; ni < NB; ni += gridDim.x * blockDim.x){
        const float* pp = p + ((size_t)bi * NB + ni) * 3;
        m0 = fminf(m0, pp[0]); m1 = fminf(m1, pp[1]); m2 = fminf(m2, pp[2]);
    }
    #pragma unroll
    for (int o = 32; o > 0; o >>= 1){
        m0 = fminf(m0, __shfl_down(m0, o, 64));
        m1 = fminf(m1, __shfl_down(m1, o, 64));
        m2 = fminf(m2, __shfl_down(m2, o, 64));
    }
    if ((threadIdx.x & 63) == 0){
        // positive floats: int compare == float compare
        atomicMin((int*)(pmin + bi*3 + 0), __float_as_int(m0));
        atomicMin((int*)(pmin + bi*3 + 1), __float_as_int(m1));
        atomicMin((int*)(pmin + bi*3 + 2), __float_as_int(m2));
    }
}

// ---------------------------------------------------------------- out init (b2 broadcast)
__global__ void init_out_kernel(float* __restrict__ out, const float* __restrict__ b2){
    int t = blockIdx.x * blockDim.x + threadIdx.x;
    out[t] = b2[t & 127];
}

// ---------------------------------------------------------------- voxel scatter (atomicMax of ids)
// Voxelization in FLOAT64: floor((double)p / g_d), matching a numpy f64 reference.
__global__ void scatter_kernel(const float* __restrict__ p, const float* __restrict__ pmin,
                               int* __restrict__ vgrid, int* __restrict__ gcbuf,
                               double gd, int D){
    int m  = blockIdx.x * blockDim.x + threadIdx.x;
    int bi = m >> 16;
    double px = (double)p[m*3], py = (double)p[m*3+1], pz = (double)p[m*3+2];
    int gx = (int)floor(px / gd) - (int)floor((double)pmin[bi*3+0] / gd);
    int gy = (int)floor(py / gd) - (int)floor((double)pmin[bi*3+1] / gd);
    int gz = (int)floor(pz / gd) - (int)floor((double)pmin[bi*3+2] / gd);
    gcbuf[m] = (gx << 20) | (gy << 10) | gz;
    atomicMax(vgrid + (((bi * D + gx) * D + gy) * D + gz), m);
}

// ---------------------------------------------------------------- 27-tap neighbor table
__global__ void nbr_kernel(const int* __restrict__ gcbuf, const int* __restrict__ vgrid,
                           int* __restrict__ nbr, int D){
    int m  = blockIdx.x * blockDim.x + threadIdx.x;
    int bi = m >> 16;
    int pk = gcbuf[m];
    int gx = pk >> 20, gy = (pk >> 10) & 1023, gz = pk & 1023;
    #pragma unroll
    for (int k = 0; k < 27; k++){
        int v;
        if (k == 13){
            v = m;                                   // center tap: always self
        } else {
            int x = gx + (k/9) - 1;
            int y = gy + ((k/3)%3) - 1;
            int z = gz + (k%3) - 1;
            if (x < 0 || y < 0 || z < 0 || x >= D || y >= D || z >= D) v = -1;
            else v = vgrid[((bi * D + x) * D + y) * D + z];
        }
        nbr[k * MTOT + m] = v;
    }
}

// ---------------------------------------------------------------- fused mlp1 + per-scale mlp
// h0[m,c] = b[c] + sum_j (b1[j] + p[m]·w1[:,j]) * w[j,c]
__global__ void mlp_scale_kernel(const float* __restrict__ p, const float* __restrict__ w1,
                                 const float* __restrict__ b1,
                                 const float* __restrict__ w, const float* __restrict__ b,
                                 float* __restrict__ h0){
    int t = blockIdx.x * blockDim.x + threadIdx.x;
    int c = t & 31, m = t >> 5;
    float x = p[m*3+0], y = p[m*3+1], z = p[m*3+2];
    float acc = b[c];
    #pragma unroll
    for (int j = 0; j < 32; j++){
        float ptsj = b1[j] + x * w1[j] + y * w1[32 + j] + z * w1[64 + j];
        acc += ptsj * w[j*32 + c];
    }
    h0[t] = acc;
}

// ---------------------------------------------------------------- submanifold conv
// MODE 0: hout = conv(f) + f                     (h1 = conv(h0)+h0)
// MODE 1: out += (conv(f) + f + h0) @ w2i        (outs_i @ w2 slice, accumulated)
template<int MODE>
__global__ __launch_bounds__(256)
void conv_kernel(const float* __restrict__ f, const float* __restrict__ W,
                 const float* __restrict__ bias, const int* __restrict__ nbr,
                 const float* __restrict__ h0, const float* __restrict__ w2i,
                 float* __restrict__ hout, float* __restrict__ out)
{
    int m = blockIdx.x * blockDim.x + threadIdx.x;
    float acc[32];
    #pragma unroll
    for (int c = 0; c < 32; c++) acc[c] = bias[c];

    #pragma unroll 1
    for (int k = 0; k < 27; k++){
        int nb = nbr[k * MTOT + m];
        if (nb < 0) continue;
        const float4* fr = (const float4*)(f + (size_t)nb * 32);
        const float*  Wk = W + k * 1024;            // [32 in][32 out]
        #pragma unroll
        for (int jq = 0; jq < 8; jq++){
            float4 fv = fr[jq];
            #pragma unroll
            for (int c = 0; c < 32; c++){
                acc[c] += fv.x * Wk[(jq*4+0)*32 + c];
                acc[c] += fv.y * Wk[(jq*4+1)*32 + c];
                acc[c] += fv.z * Wk[(jq*4+2)*32 + c];
                acc[c] += fv.w * Wk[(jq*4+3)*32 + c];
            }
        }
    }

    const float* frow = f + (size_t)m * 32;
    if (MODE == 0){
        float* ho = hout + (size_t)m * 32;
        #pragma unroll
        for (int c = 0; c < 32; c++) ho[c] = acc[c] + frow[c];
    } else {
        const float* h0row = h0 + (size_t)m * 32;
        float v[32];
        #pragma unroll
        for (int c = 0; c < 32; c++) v[c] = acc[c] + frow[c] + h0row[c];
        float* orow = out + (size_t)m * 128;
        #pragma unroll 1
        for (int ch = 0; ch < 4; ch++){            // 128 outputs in 4 chunks of 32
            float o32[32];
            #pragma unroll
            for (int q = 0; q < 8; q++){
                float4 t4 = ((const float4*)orow)[ch*8 + q];
                o32[q*4+0] = t4.x; o32[q*4+1] = t4.y; o32[q*4+2] = t4.z; o32[q*4+3] = t4.w;
            }
            #pragma unroll
            for (int c = 0; c < 32; c++){
                float vc = v[c];
                const float* w2r = w2i + c*128 + ch*32;
                #pragma unroll
                for (int o = 0; o < 32; o++) o32[o] += vc * w2r[o];
            }
            #pragma unroll
            for (int q = 0; q < 8; q++){
                ((float4*)orow)[ch*8 + q] =
                    make_float4(o32[q*4+0], o32[q*4+1], o32[q*4+2], o32[q*4+3]);
            }
        }
    }
}

// ---------------------------------------------------------------- launch
extern "C" void kernel_launch(void* const* d_in, const int* in_sizes, int n_in,
                              void* d_out, int out_size, void* d_ws, size_t ws_size,
                              hipStream_t stream)
{
    // Bind inputs by unique element count (robust to ordering), positional fallback.
    static const int want[9] = {393216, 96, 32, 8192, 256, 442368, 512, 32768, 128};
    const void* bound[9];
    for (int i = 0; i < 9; i++) bound[i] = d_in[i];
    if (n_in == 9){
        for (int i = 0; i < 9; i++)
            for (int j = 0; j < 9; j++)
                if (in_sizes[j] == want[i]) { bound[i] = d_in[j]; break; }
    }
    const float* p      = (const float*)bound[0];
    const float* w1     = (const float*)bound[1];
    const float* b1     = (const float*)bound[2];
    const float* w_mlp  = (const float*)bound[3];
    const float* b_mlp  = (const float*)bound[4];
    const float* w_conv = (const float*)bound[5];
    const float* b_conv = (const float*)bound[6];
    const float* w2     = (const float*)bound[7];
    const float* b2     = (const float*)bound[8];
    float* out = (float*)d_out;

    // Compact workspace layout: 46 MiB total.
    //   h0   : [0, 16M)
    //   h1   : [16M, 32M)   — vgrid aliases its first 8.25 MB (lifetime-disjoint)
    //   nbr  : [32M, +13.5M), gcbuf: +0.5M, pmin: +256B
    char* ws = (char*)d_ws;
    float* h0    = (float*)(ws);
    float* h1    = (float*)(ws + 16777216);
    int*   vgrid = (int*)  (ws + 16777216);                 // alias of h1
    int*   nbr   = (int*)  (ws + 33554432);                 // 14,155,776 B
    int*   gcbuf = (int*)  (ws + 33554432 + 14155776);      // 524,288 B
    float* pmin  = (float*)(ws + 33554432 + 14155776 + 524288);

    static const double GS[8] = {0.01, 0.02, 0.04, 0.08, 0.16, 0.32, 0.64, 1.28};
    static const int    DS[8] = {101, 51, 26, 14, 8, 5, 3, 2};   // ceil(1/g)+1 (double semantics)

    pmin_init_kernel<<<1, 64, 0, stream>>>(pmin);
    pmin_kernel<<<dim3(64, 2), 256, 0, stream>>>(p, pmin);
    init_out_kernel<<<(MTOT*128)/256, 256, 0, stream>>>(out, b2);

    for (int i = 0; i < 8; i++){
        int D = DS[i]; double gd = GS[i];
        hipMemsetAsync(vgrid, 0xFF, (size_t)2*D*D*D*sizeof(int), stream);
        scatter_kernel<<<MTOT/256, 256, 0, stream>>>(p, pmin, vgrid, gcbuf, gd, D);
        nbr_kernel<<<MTOT/256, 256, 0, stream>>>(gcbuf, vgrid, nbr, D);
        mlp_scale_kernel<<<(MTOT*32)/256, 256, 0, stream>>>(p, w1, b1, w_mlp + i*1024, b_mlp + i*32, h0);
        conv_kernel<0><<<MTOT/256, 256, 0, stream>>>(
            h0, w_conv + (size_t)(2*i)*27648, b_conv + (2*i)*32, nbr,
            nullptr, nullptr, h1, nullptr);
        conv_kernel<1><<<MTOT/256, 256, 0, stream>>>(
            h1, w_conv + (size_t)(2*i+1)*27648, b_conv + (2*i+1)*32, nbr,
            h0, w2 + i*32*128, nullptr, out);
    }
}

// Round 4
// 2943.125 us; speedup vs baseline: 1.7058x; 1.7058x over previous
//
#include <hip/hip_runtime.h>

#define MTOT 131072   // b*n
#define NB   65536    // n per batch

// ---------------------------------------------------------------- pmin
__global__ void pmin_init_kernel(float* pmin){
    if (threadIdx.x < 6) pmin[threadIdx.x] = 2.0f;   // p in [0,1)
}

__global__ void pmin_kernel(const float* __restrict__ p, float* __restrict__ pmin){
    int bi = blockIdx.y;
    float m0 = 2.f, m1 = 2.f, m2 = 2.f;
    for (int ni = blockIdx.x * blockDim.x + threadIdx.x; ni < NB; ni += gridDim.x * blockDim.x){
        const float* pp = p + ((size_t)bi * NB + ni) * 3;
        m0 = fminf(m0, pp[0]); m1 = fminf(m1, pp[1]); m2 = fminf(m2, pp[2]);
    }
    #pragma unroll
    for (int o = 32; o > 0; o >>= 1){
        m0 = fminf(m0, __shfl_down(m0, o, 64));
        m1 = fminf(m1, __shfl_down(m1, o, 64));
        m2 = fminf(m2, __shfl_down(m2, o, 64));
    }
    if ((threadIdx.x & 63) == 0){
        // positive floats: int compare == float compare
        atomicMin((int*)(pmin + bi*3 + 0), __float_as_int(m0));
        atomicMin((int*)(pmin + bi*3 + 1), __float_as_int(m1));
        atomicMin((int*)(pmin + bi*3 + 2), __float_as_int(m2));
    }
}

// ---------------------------------------------------------------- out init (b2 broadcast)
__global__ void init_out_kernel(float* __restrict__ out, const float* __restrict__ b2){
    int t = blockIdx.x * blockDim.x + threadIdx.x;
    out[t] = b2[t & 127];
}

// ---------------------------------------------------------------- voxel scatter (atomicMax of ids)
// Voxelization in FLOAT64: floor((double)p / g_d), matching the numpy f64 reference.
// USE_LDS=1 (coarse scales, D^3 <= 2744): two-level scatter — per-block LDS grid
// absorbs same-address contention (g=1.28 puts ALL 65536 pts/batch in ONE voxel;
// direct global atomicMax serialized 65536 RMWs = the 1.49 ms stall in round-3 profile).
// Result bit-identical: max is associative/commutative.
template<int USE_LDS>
__global__ void scatter_kernel(const float* __restrict__ p, const float* __restrict__ pmin,
                               int* __restrict__ vgrid, int* __restrict__ gcbuf,
                               double gd, int D){
    extern __shared__ int lgrid[];
    int m  = blockIdx.x * blockDim.x + threadIdx.x;
    int bi = m >> 16;                                  // 256 | 65536 -> block spans one batch
    double px = (double)p[m*3], py = (double)p[m*3+1], pz = (double)p[m*3+2];
    int gx = (int)floor(px / gd) - (int)floor((double)pmin[bi*3+0] / gd);
    int gy = (int)floor(py / gd) - (int)floor((double)pmin[bi*3+1] / gd);
    int gz = (int)floor(pz / gd) - (int)floor((double)pmin[bi*3+2] / gd);
    gcbuf[m] = (gx << 20) | (gy << 10) | gz;
    int cell = (gx * D + gy) * D + gz;

    if (!USE_LDS){
        atomicMax(vgrid + bi * D * D * D + cell, m);
        return;
    }
    int ncell = D * D * D;
    for (int c = threadIdx.x; c < ncell; c += 256) lgrid[c] = -1;
    __syncthreads();
    atomicMax(&lgrid[cell], m);
    __syncthreads();
    int* vg = vgrid + bi * ncell;
    for (int c = threadIdx.x; c < ncell; c += 256){
        int v = lgrid[c];
        if (v >= 0) atomicMax(vg + c, v);
    }
}

// ---------------------------------------------------------------- 27-tap neighbor table
__global__ void nbr_kernel(const int* __restrict__ gcbuf, const int* __restrict__ vgrid,
                           int* __restrict__ nbr, int D){
    int m  = blockIdx.x * blockDim.x + threadIdx.x;
    int bi = m >> 16;
    int pk = gcbuf[m];
    int gx = pk >> 20, gy = (pk >> 10) & 1023, gz = pk & 1023;
    #pragma unroll
    for (int k = 0; k < 27; k++){
        int v;
        if (k == 13){
            v = m;                                   // center tap: always self
        } else {
            int x = gx + (k/9) - 1;
            int y = gy + ((k/3)%3) - 1;
            int z = gz + (k%3) - 1;
            if (x < 0 || y < 0 || z < 0 || x >= D || y >= D || z >= D) v = -1;
            else v = vgrid[((bi * D + x) * D + y) * D + z];
        }
        nbr[k * MTOT + m] = v;
    }
}

// ---------------------------------------------------------------- fused mlp1 + per-scale mlp
// h0[m,c] = b[c] + sum_j (b1[j] + p[m]·w1[:,j]) * w[j,c]
__global__ void mlp_scale_kernel(const float* __restrict__ p, const float* __restrict__ w1,
                                 const float* __restrict__ b1,
                                 const float* __restrict__ w, const float* __restrict__ b,
                                 float* __restrict__ h0){
    int t = blockIdx.x * blockDim.x + threadIdx.x;
    int c = t & 31, m = t >> 5;
    float x = p[m*3+0], y = p[m*3+1], z = p[m*3+2];
    float acc = b[c];
    #pragma unroll
    for (int j = 0; j < 32; j++){
        float ptsj = b1[j] + x * w1[j] + y * w1[32 + j] + z * w1[64 + j];
        acc += ptsj * w[j*32 + c];
    }
    h0[t] = acc;
}

// ---------------------------------------------------------------- submanifold conv
// MODE 0: hout = conv(f) + f                     (h1 = conv(h0)+h0)
// MODE 1: out += (conv(f) + f + h0) @ w2i        (outs_i @ w2 slice, accumulated)
template<int MODE>
__global__ __launch_bounds__(256)
void conv_kernel(const float* __restrict__ f, const float* __restrict__ W,
                 const float* __restrict__ bias, const int* __restrict__ nbr,
                 const float* __restrict__ h0, const float* __restrict__ w2i,
                 float* __restrict__ hout, float* __restrict__ out)
{
    int m = blockIdx.x * blockDim.x + threadIdx.x;
    float acc[32];
    #pragma unroll
    for (int c = 0; c < 32; c++) acc[c] = bias[c];

    #pragma unroll 1
    for (int k = 0; k < 27; k++){
        int nb = nbr[k * MTOT + m];
        if (nb < 0) continue;
        const float4* fr = (const float4*)(f + (size_t)nb * 32);
        const float*  Wk = W + k * 1024;            // [32 in][32 out]
        #pragma unroll
        for (int jq = 0; jq < 8; jq++){
            float4 fv = fr[jq];
            #pragma unroll
            for (int c = 0; c < 32; c++){
                acc[c] += fv.x * Wk[(jq*4+0)*32 + c];
                acc[c] += fv.y * Wk[(jq*4+1)*32 + c];
                acc[c] += fv.z * Wk[(jq*4+2)*32 + c];
                acc[c] += fv.w * Wk[(jq*4+3)*32 + c];
            }
        }
    }

    const float* frow = f + (size_t)m * 32;
    if (MODE == 0){
        float* ho = hout + (size_t)m * 32;
        #pragma unroll
        for (int c = 0; c < 32; c++) ho[c] = acc[c] + frow[c];
    } else {
        const float* h0row = h0 + (size_t)m * 32;
        float v[32];
        #pragma unroll
        for (int c = 0; c < 32; c++) v[c] = acc[c] + frow[c] + h0row[c];
        float* orow = out + (size_t)m * 128;
        #pragma unroll 1
        for (int ch = 0; ch < 4; ch++){            // 128 outputs in 4 chunks of 32
            float o32[32];
            #pragma unroll
            for (int q = 0; q < 8; q++){
                float4 t4 = ((const float4*)orow)[ch*8 + q];
                o32[q*4+0] = t4.x; o32[q*4+1] = t4.y; o32[q*4+2] = t4.z; o32[q*4+3] = t4.w;
            }
            #pragma unroll
            for (int c = 0; c < 32; c++){
                float vc = v[c];
                const float* w2r = w2i + c*128 + ch*32;
                #pragma unroll
                for (int o = 0; o < 32; o++) o32[o] += vc * w2r[o];
            }
            #pragma unroll
            for (int q = 0; q < 8; q++){
                ((float4*)orow)[ch*8 + q] =
                    make_float4(o32[q*4+0], o32[q*4+1], o32[q*4+2], o32[q*4+3]);
            }
        }
    }
}

// ---------------------------------------------------------------- launch
extern "C" void kernel_launch(void* const* d_in, const int* in_sizes, int n_in,
                              void* d_out, int out_size, void* d_ws, size_t ws_size,
                              hipStream_t stream)
{
    // Bind inputs by unique element count (robust to ordering), positional fallback.
    static const int want[9] = {393216, 96, 32, 8192, 256, 442368, 512, 32768, 128};
    const void* bound[9];
    for (int i = 0; i < 9; i++) bound[i] = d_in[i];
    if (n_in == 9){
        for (int i = 0; i < 9; i++)
            for (int j = 0; j < 9; j++)
                if (in_sizes[j] == want[i]) { bound[i] = d_in[j]; break; }
    }
    const float* p      = (const float*)bound[0];
    const float* w1     = (const float*)bound[1];
    const float* b1     = (const float*)bound[2];
    const float* w_mlp  = (const float*)bound[3];
    const float* b_mlp  = (const float*)bound[4];
    const float* w_conv = (const float*)bound[5];
    const float* b_conv = (const float*)bound[6];
    const float* w2     = (const float*)bound[7];
    const float* b2     = (const float*)bound[8];
    float* out = (float*)d_out;

    // Compact workspace layout: 46 MiB total.
    //   h0   : [0, 16M)
    //   h1   : [16M, 32M)   — vgrid aliases its first 8.25 MB (lifetime-disjoint)
    //   nbr  : [32M, +13.5M), gcbuf: +0.5M, pmin: +256B
    char* ws = (char*)d_ws;
    float* h0    = (float*)(ws);
    float* h1    = (float*)(ws + 16777216);
    int*   vgrid = (int*)  (ws + 16777216);                 // alias of h1
    int*   nbr   = (int*)  (ws + 33554432);                 // 14,155,776 B
    int*   gcbuf = (int*)  (ws + 33554432 + 14155776);      // 524,288 B
    float* pmin  = (float*)(ws + 33554432 + 14155776 + 524288);

    static const double GS[8] = {0.01, 0.02, 0.04, 0.08, 0.16, 0.32, 0.64, 1.28};
    static const int    DS[8] = {101, 51, 26, 14, 8, 5, 3, 2};   // ceil(1/g)+1 (double semantics)

    pmin_init_kernel<<<1, 64, 0, stream>>>(pmin);
    pmin_kernel<<<dim3(64, 2), 256, 0, stream>>>(p, pmin);
    init_out_kernel<<<(MTOT*128)/256, 256, 0, stream>>>(out, b2);

    for (int i = 0; i < 8; i++){
        int D = DS[i]; double gd = GS[i];
        int ncell = D * D * D;
        hipMemsetAsync(vgrid, 0xFF, (size_t)2*ncell*sizeof(int), stream);
        if (ncell <= 2744)   // coarse scales: LDS two-level scatter (kills atomic contention)
            scatter_kernel<1><<<MTOT/256, 256, ncell*sizeof(int), stream>>>(p, pmin, vgrid, gcbuf, gd, D);
        else
            scatter_kernel<0><<<MTOT/256, 256, 0, stream>>>(p, pmin, vgrid, gcbuf, gd, D);
        nbr_kernel<<<MTOT/256, 256, 0, stream>>>(gcbuf, vgrid, nbr, D);
        mlp_scale_kernel<<<(MTOT*32)/256, 256, 0, stream>>>(p, w1, b1, w_mlp + i*1024, b_mlp + i*32, h0);
        conv_kernel<0><<<MTOT/256, 256, 0, stream>>>(
            h0, w_conv + (size_t)(2*i)*27648, b_conv + (2*i)*32, nbr,
            nullptr, nullptr, h1, nullptr);
        conv_kernel<1><<<MTOT/256, 256, 0, stream>>>(
            h1, w_conv + (size_t)(2*i+1)*27648, b_conv + (2*i+1)*32, nbr,
            h0, w2 + i*32*128, nullptr, out);
    }
}